// Round 4
// baseline (206.925 us; speedup 1.0000x reference)
//
#include <hip/hip_runtime.h>
#include <cstdint>

typedef float float4v __attribute__((ext_vector_type(4)));

__device__ __forceinline__ uint32_t mono32(float x) {
    int32_t b = __float_as_int(x);
    return (uint32_t)(b ^ ((b >> 31) | 0x80000000));
}

// async global->LDS, 16B/lane; LDS dest = wave-uniform base + lane*16
__device__ __forceinline__ void gll16(const float* g, float* l) {
    __builtin_amdgcn_global_load_lds((const __attribute__((address_space(1))) void*)g,
                                     (__attribute__((address_space(3))) void*)l, 16, 0, 0);
}

// One wave per block, one thread per row, 64 rows. Input tile staged in four
// 16-column quarters (8 KB each incl. noise), double-buffered -> 16 KB LDS,
// 10 blocks/CU. Quarter c, instr k, lane l stages global
// (row = 16k + (l>>2), quad = (l&3)^((l>>3)&3)) of quarter c into linear unit
// 64k+l; owner thread t reads quad j at unit 4t + (j^((t>>1)&3)) -> 8 bank
// groups, conflict level == R3 (measured negligible).

#define ISSUE_Q(c)                                                             \
    {                                                                          \
        _Pragma("unroll")                                                      \
        for (int k = 0; k < 4; ++k) {                                          \
            uint32_t gofs = (uint32_t)(row0 + 16 * k + rl) * 64u               \
                          + (uint32_t)(c) * 16u + (uint32_t)qd * 4u;           \
            gll16(gin + gofs, &qA[(c) & 1][k * 256]);                          \
            gll16(gnz + gofs, &qB[(c) & 1][k * 256]);                          \
        }                                                                      \
    }

#define CONSUME_Q(c)                                                           \
    {                                                                          \
        _Pragma("unroll")                                                      \
        for (int j = 0; j < 4; ++j) {                                          \
            const int u = 4 * t + (j ^ sw2);                                   \
            float4v a = *(const float4v*)&qA[(c) & 1][u * 4];                  \
            float4v b = *(const float4v*)&qB[(c) & 1][u * 4];                  \
            _Pragma("unroll")                                                  \
            for (int i = 0; i < 4; ++i) {                                      \
                const int e = (c) * 16 + j * 4 + i;                            \
                float s = a[i] + b[i];                                         \
                vin[e]  = a[i];                                                \
                keys[e] = s;                                                   \
                _Pragma("unroll")                                              \
                for (int u8 = 0; u8 < 8; ++u8) {                               \
                    float h = heap[u8];                                        \
                    heap[u8] = fmaxf(h, s);                                    \
                    s        = fminf(h, s);                                    \
                }                                                              \
            }                                                                  \
        }                                                                      \
    }

__global__ __launch_bounds__(64, 2)
void gumbel_topk_softmax_kernel(const float* __restrict__ gin,
                                const float* __restrict__ gnz,
                                float* __restrict__ gout) {
    __shared__ __align__(16) float qA[2][1024];   // inputs, double-buffered quarter
    __shared__ __align__(16) float qB[2][1024];   // noise

    const int t    = threadIdx.x;                 // 0..63 = local row
    const int row0 = blockIdx.x * 64;
    const int rl   = t >> 2;                      // staging source row-in-group
    const int qd   = (t & 3) ^ ((t >> 3) & 3);    // staging source quad (pre-swizzled)
    const int sw2  = (t >> 1) & 3;                // owner-read swizzle

    float vin[64];    // original inputs (static-indexed)
    float keys[64];   // z = in + noise
    float heap[8];
#pragma unroll
    for (int q = 0; q < 8; ++q) heap[q] = -INFINITY;

    // ---- quarter-pipelined stage+consume; syncs are per-wave drains ----
    ISSUE_Q(0);
    __syncthreads();
    ISSUE_Q(1);
    CONSUME_Q(0);
    __syncthreads();
    ISSUE_Q(2);
    CONSUME_Q(1);
    __syncthreads();
    ISSUE_Q(3);
    CONSUME_Q(2);
    __syncthreads();
    CONSUME_Q(3);

    // ---- selection: threshold fast path, exact u64 fallback on f32 ties ----
    const float T = heap[7];
    int cnt = 0;
    uint32_t mlo = 0u, mhi = 0u;
#pragma unroll
    for (int j = 0; j < 64; ++j) {
        bool ge = keys[j] >= T;
        cnt += ge ? 1 : 0;
        if (j < 32) mlo |= ge ? (1u << j) : 0u;
        else        mhi |= ge ? (1u << (j - 32)) : 0u;
    }
    if (cnt != 8) {
        // cold (~3e-5 of rows): f32 tie at rank-8 boundary. Exact f64 order via
        // u64 key = [mono(s) | mono(2Sum residual)>>6 | 63-j]; noise re-read
        // from global (quarter buffers already recycled).
        unsigned long long h8[8];
#pragma unroll
        for (int q = 0; q < 8; ++q) h8[q] = 0ull;
        const float* brow = gnz + (size_t)(row0 + t) * 64;
#pragma unroll
        for (int j = 0; j < 64; ++j) {
            float a = vin[j], b = brow[j];
            float s  = a + b;
            float ap = s - b;
            float bp = s - ap;
            float res = (a - ap) + (b - bp);
            unsigned long long key = ((unsigned long long)mono32(s) << 32)
                                   | ((unsigned long long)(mono32(res) >> 6) << 6)
                                   | (unsigned long long)(63 - j);
#pragma unroll
            for (int q = 0; q < 8; ++q) {
                unsigned long long hq = h8[q];
                unsigned long long mx = key > hq ? key : hq;
                key   = key > hq ? hq : key;
                h8[q] = mx;
            }
        }
        mlo = mhi = 0u;
#pragma unroll
        for (int q = 0; q < 8; ++q) {
            int j = 63 - (int)(h8[q] & 63ull);
            if (j < 32) mlo |= 1u << j;
            else        mhi |= 1u << (j - 32);
        }
    }

    // ---- softmax over selected ORIGINAL inputs (no shift: |in| < ~6) ----
    float ssum = 0.f;
#pragma unroll
    for (int j = 0; j < 64; ++j) {
        uint32_t bit = (j < 32 ? (mlo >> j) : (mhi >> (j - 32))) & 1u;
        float ev = __expf(vin[j]) * (float)bit;
        ssum += ev;
        vin[j] = ev;
    }
    const float inv = 1.0f / ssum;

    // ---- direct row stores: each 64B line fully written by one thread ----
    float4v* orow = (float4v*)(gout + (size_t)(row0 + t) * 64);
#pragma unroll
    for (int q = 0; q < 16; ++q) {
        float4v v;
#pragma unroll
        for (int i = 0; i < 4; ++i) v[i] = vin[q * 4 + i] * inv;
        orow[q] = v;
    }
}

extern "C" void kernel_launch(void* const* d_in, const int* in_sizes, int n_in,
                              void* d_out, int out_size, void* d_ws, size_t ws_size,
                              hipStream_t stream) {
    const float* gin = (const float*)d_in[0];
    const float* gnz = (const float*)d_in[1];
    float* gout = (float*)d_out;
    const int nrows = in_sizes[0] / 64;        // 1,048,576
    const int grid  = nrows / 64;              // 16384 single-wave blocks
    gumbel_topk_softmax_kernel<<<grid, 64, 0, stream>>>(gin, gnz, gout);
}